// Round 3
// baseline (1359.070 us; speedup 1.0000x reference)
//
#include <hip/hip_runtime.h>

#define E_EXP 4
#define D_MODEL 1024
#define B_BATCH 4
#define S_SEQ 4096
#define NTOK (B_BATCH*S_SEQ)   // 16384
#define CHUNK 32
#define NCHUNK (S_SEQ/CHUNK)   // 128

typedef float f4 __attribute__((ext_vector_type(4)));
typedef float f32x4 __attribute__((ext_vector_type(4)));
typedef short bf16x8 __attribute__((ext_vector_type(8)));

__device__ __forceinline__ unsigned short f2b(float f){
  union{float f;unsigned u;}v; v.f=f;
  unsigned r = v.u + 0x7fffu + ((v.u>>16)&1u);
  return (unsigned short)(r>>16);
}
__device__ __forceinline__ float b2f_lo(unsigned v){ union{unsigned u;float f;}x; x.u=v<<16; return x.f; }
__device__ __forceinline__ float b2f_hi(unsigned v){ union{unsigned u;float f;}x; x.u=v&0xffff0000u; return x.f; }

__device__ __forceinline__ void gload_lds16(const void* g, void* l){
  __builtin_amdgcn_global_load_lds(
      (const __attribute__((address_space(1))) void*)g,
      (__attribute__((address_space(3))) void*)l, 16, 0, 0);
}

// ---------------- fp32 -> bf16 conversion (flat) ----------------
__global__ __launch_bounds__(256) void cvt_bf16(const float* __restrict__ src,
                                                unsigned short* __restrict__ dst)
{
  size_t i = ((size_t)blockIdx.x*256 + threadIdx.x)*4;
  f4 v = *(const f4*)(src + i);
  ushort4 o; o.x=f2b(v[0]); o.y=f2b(v[1]); o.z=f2b(v[2]); o.w=f2b(v[3]);
  *(ushort4*)(dst + i) = o;
}

// weight slice -> interleaved Wcat[le][3][D][D]
__global__ __launch_bounds__(256) void cvt_w(const float* __restrict__ W,
                                             unsigned short* __restrict__ Wcat,
                                             int e0, int mat)
{
  size_t i4 = ((size_t)blockIdx.x*256 + threadIdx.x)*4;
  size_t le  = i4 >> 20;                 // / (D*D)
  size_t rem = i4 & ((1u<<20)-1);
  f4 v = *(const f4*)(W + (size_t)(e0+le)*D_MODEL*D_MODEL + rem);
  ushort4 o; o.x=f2b(v[0]); o.y=f2b(v[1]); o.z=f2b(v[2]); o.w=f2b(v[3]);
  *(ushort4*)(Wcat + (le*3 + mat)*((size_t)D_MODEL*D_MODEL) + rem) = o;
}

// ---------------- router: top-2 softmax gate weights per token ----------------
__global__ __launch_bounds__(256) void router_kernel(
    const float* __restrict__ x, const float* __restrict__ Wgate,
    float* __restrict__ wtok)
{
  int gtid = blockIdx.x*256 + threadIdx.x;
  int tok  = gtid >> 6;
  int lane = threadIdx.x & 63;
  const float* xr = x + (size_t)tok * D_MODEL;
  float acc0=0.f,acc1=0.f,acc2=0.f,acc3=0.f;
  for (int k=lane;k<D_MODEL;k+=64){
    float xv = xr[k];
    acc0 += xv*Wgate[0*D_MODEL+k];
    acc1 += xv*Wgate[1*D_MODEL+k];
    acc2 += xv*Wgate[2*D_MODEL+k];
    acc3 += xv*Wgate[3*D_MODEL+k];
  }
  #pragma unroll
  for (int off=32;off>0;off>>=1){
    acc0 += __shfl_down(acc0,off);
    acc1 += __shfl_down(acc1,off);
    acc2 += __shfl_down(acc2,off);
    acc3 += __shfl_down(acc3,off);
  }
  if (lane==0){
    float l[4]={acc0,acc1,acc2,acc3};
    int i1=0;
    #pragma unroll
    for(int e=1;e<4;e++) if (l[e]>l[i1]) i1=e;
    int i2=-1;
    #pragma unroll
    for(int e=0;e<4;e++){ if(e==i1) continue; if(i2<0||l[e]>l[i2]) i2=e; }
    float ex = __expf(l[i2]-l[i1]);
    float w1 = 1.f/(1.f+ex);
    float w2 = ex/(1.f+ex);
    float w[4]={0.f,0.f,0.f,0.f};
    w[i1]=w1; w[i2]=w2;
    float* wp = wtok + (size_t)tok*E_EXP;
    wp[0]=w[0]; wp[1]=w[1]; wp[2]=w[2]; wp[3]=w[3];
  }
}

// ---------------- fused bf16 MFMA GEMM: g,v,d in one pass ----------------
// For tile (m,n): G=x@Wg^T+bg, V=x@Wv^T+bv, Dd=x@Wd^T+bd
// xs = bf16(sigmoid(G)*tanh(V));  aa = bf16(0.001+0.998*sigmoid(Dd))
#define BM 128
#define BN 64
#define BK 32

__global__ __launch_bounds__(256) void gemm_fused(
    const unsigned short* __restrict__ A,     // xbf [NTOK][D]
    const unsigned short* __restrict__ Wcat,  // [G][3][D][D] bf16
    const float* __restrict__ bg, const float* __restrict__ bv,
    const float* __restrict__ bd,
    unsigned short* __restrict__ xs, unsigned short* __restrict__ aa,
    int e0)
{
  __shared__ unsigned short sA[BM*BK];       // 8 KB
  __shared__ unsigned short sB[3*BN*BK];     // 12 KB
  int le = blockIdx.z;
  int mbase = blockIdx.x*BM, nbase = blockIdx.y*BN;
  int tid  = threadIdx.x;
  int wave = tid>>6, lane = tid&63;
  int wm = wave>>1, wn = wave&1;             // 2x2 wave grid, wave tile 64x32

  const size_t DD = (size_t)D_MODEL*D_MODEL;
  const unsigned short* We = Wcat + (size_t)le*3*DD;

  // staging map: each gload_lds16 stages 16 rows x 64B (lane>>2 row, (lane&3)*8 col)
  int srow = lane>>2;
  int scol = (lane&3)*8;
  const unsigned short* gA0 = A + (size_t)(mbase + wave*16 + srow)*D_MODEL + scol;
  const unsigned short* gA1 = gA0 + (size_t)64*D_MODEL;   // rows +64
  const unsigned short* gB0 = We + 0*DD + (size_t)(nbase + wave*16 + srow)*D_MODEL + scol;
  const unsigned short* gB1 = We + 1*DD + (size_t)(nbase + wave*16 + srow)*D_MODEL + scol;
  const unsigned short* gB2 = We + 2*DD + (size_t)(nbase + wave*16 + srow)*D_MODEL + scol;
  unsigned short* lA0 = &sA[(wave*16)*BK];
  unsigned short* lA1 = &sA[(wave*16+64)*BK];
  unsigned short* lB0 = &sB[0*BN*BK + (wave*16)*BK];
  unsigned short* lB1 = &sB[1*BN*BK + (wave*16)*BK];
  unsigned short* lB2 = &sB[2*BN*BK + (wave*16)*BK];

  f32x4 accG[4][2], accV[4][2], accD[4][2];
  #pragma unroll
  for (int i=0;i<4;i++)
    #pragma unroll
    for (int j=0;j<2;j++){ accG[i][j]=0; accV[i][j]=0; accD[i][j]=0; }

  int arow = wm*64 + (lane&15);
  int brow = wn*32 + (lane&15);
  int kfr  = (lane>>4)*8;

  for (int k0=0; k0<D_MODEL; k0+=BK){
    gload_lds16(gA0 + k0, lA0);
    gload_lds16(gA1 + k0, lA1);
    gload_lds16(gB0 + k0, lB0);
    gload_lds16(gB1 + k0, lB1);
    gload_lds16(gB2 + k0, lB2);
    __syncthreads();
    bf16x8 af[4];
    #pragma unroll
    for (int mi=0;mi<4;mi++) af[mi] = *(const bf16x8*)&sA[(arow + mi*16)*BK + kfr];
    #pragma unroll
    for (int ni=0;ni<2;ni++){
      bf16x8 b0 = *(const bf16x8*)&sB[0*BN*BK + (brow + ni*16)*BK + kfr];
      bf16x8 b1 = *(const bf16x8*)&sB[1*BN*BK + (brow + ni*16)*BK + kfr];
      bf16x8 b2 = *(const bf16x8*)&sB[2*BN*BK + (brow + ni*16)*BK + kfr];
      #pragma unroll
      for (int mi=0;mi<4;mi++){
        accG[mi][ni] = __builtin_amdgcn_mfma_f32_16x16x32_bf16(af[mi], b0, accG[mi][ni], 0, 0, 0);
        accV[mi][ni] = __builtin_amdgcn_mfma_f32_16x16x32_bf16(af[mi], b1, accV[mi][ni], 0, 0, 0);
        accD[mi][ni] = __builtin_amdgcn_mfma_f32_16x16x32_bf16(af[mi], b2, accD[mi][ni], 0, 0, 0);
      }
    }
    __syncthreads();
  }

  // epilogue: C/D layout col=lane&15, row=(lane>>4)*4+r  [m89-verified]
  int e = e0 + le;
  const float* bge = bg + (size_t)e*D_MODEL;
  const float* bve = bv + (size_t)e*D_MODEL;
  const float* bde = bd + (size_t)e*D_MODEL;
  int me = mbase + wm*64;
  int ne = nbase + wn*32;
  #pragma unroll
  for (int mi=0;mi<4;mi++){
    #pragma unroll
    for (int r=0;r<4;r++){
      int m = me + mi*16 + (lane>>4)*4 + r;
      size_t rowoff = ((size_t)le*NTOK + m)*D_MODEL;
      #pragma unroll
      for (int ni=0;ni<2;ni++){
        int n = ne + ni*16 + (lane&15);
        float g = accG[mi][ni][r] + bge[n];
        float v = accV[mi][ni][r] + bve[n];
        float d = accD[mi][ni][r] + bde[n];
        float sg = 1.f/(1.f+__expf(-g));
        float th = 1.f - 2.f/(__expf(2.f*v)+1.f);
        float av = 0.001f + 0.998f/(1.f+__expf(-d));
        xs[rowoff+n] = f2b(sg*th);
        aa[rowoff+n] = f2b(av);
      }
    }
  }
}

// ---------------- chunked scan pass 1: local scan per chunk -> (P, U) ----------------
__global__ __launch_bounds__(512) void scan_pass1(
    const unsigned short* __restrict__ xs, const unsigned short* __restrict__ aa,
    float* __restrict__ P, float* __restrict__ U)
{
  int blk = blockIdx.x;
  int c  = blk % NCHUNK;
  int b  = (blk / NCHUNK) % B_BATCH;
  int le = blk / (NCHUNK*B_BATCH);
  int d0 = threadIdx.x*2;
  size_t base = (((size_t)(le*B_BATCH + b))*S_SEQ + (size_t)c*CHUNK)*D_MODEL + d0;
  float h0=0.f,h1=0.f,p0=1.f,p1=1.f;
  #pragma unroll 4
  for (int t=0;t<CHUNK;t++){
    unsigned av = *(const unsigned*)(aa + base);
    unsigned xv = *(const unsigned*)(xs + base);
    float a0=b2f_lo(av), a1=b2f_hi(av);
    float x0=b2f_lo(xv), x1=b2f_hi(xv);
    h0 = a0*h0 + x0; h1 = a1*h1 + x1;
    p0 *= a0; p1 *= a1;
    base += D_MODEL;
  }
  size_t sidx = (((size_t)(le*B_BATCH + b))*NCHUNK + c)*D_MODEL + d0;
  P[sidx]=p0; P[sidx+1]=p1;
  U[sidx]=h0; U[sidx+1]=h1;
}

// ---------------- pass 2: sequential combine over chunks -> Hinit per chunk ----------------
__global__ __launch_bounds__(256) void scan_pass2(
    const float* __restrict__ P, const float* __restrict__ U, float* __restrict__ Hinit)
{
  int ch = blockIdx.x*256 + threadIdx.x;
  int d  = ch & (D_MODEL-1);
  int eb = ch >> 10;
  size_t base = (size_t)eb*NCHUNK*D_MODEL + d;
  float H=0.f;
  for (int c=0;c<NCHUNK;c++){
    size_t idx = base + (size_t)c*D_MODEL;
    Hinit[idx] = H;
    H = P[idx]*H + U[idx];
  }
}

// ---------------- pass 3: re-scan + fused top-2 weighted combine ----------------
template<int G, int FIRST>
__global__ __launch_bounds__(512) void scan_pass3(
    const unsigned short* __restrict__ xs, const unsigned short* __restrict__ aa,
    const float* __restrict__ Hinit, const float* __restrict__ wtok,
    float* __restrict__ out, int e0)
{
  int blk = blockIdx.x;
  int c = blk % NCHUNK;
  int b = blk / NCHUNK;
  int d0 = threadIdx.x*2;
  float h[G][2];
  #pragma unroll
  for (int le=0; le<G; le++){
    size_t hi = (((size_t)(le*B_BATCH+b))*NCHUNK + c)*D_MODEL + d0;
    h[le][0]=Hinit[hi]; h[le][1]=Hinit[hi+1];
  }
  int s0 = c*CHUNK;
  for (int t=0;t<CHUNK;t++){
    size_t n = (size_t)b*S_SEQ + s0 + t;
    float o0=0.f, o1=0.f;
    #pragma unroll
    for (int le=0;le<G;le++){
      float w = wtok[n*E_EXP + e0 + le];
      size_t idx = (((size_t)(le*B_BATCH+b))*S_SEQ + (size_t)(s0 + t))*D_MODEL + d0;
      unsigned av = *(const unsigned*)(aa+idx);
      unsigned xv = *(const unsigned*)(xs+idx);
      h[le][0] = b2f_lo(av)*h[le][0] + b2f_lo(xv);
      h[le][1] = b2f_hi(av)*h[le][1] + b2f_hi(xv);
      o0 += w*h[le][0];
      o1 += w*h[le][1];
    }
    float* op = out + n*D_MODEL + d0;
    if (FIRST){ op[0]=o0;  op[1]=o1;  }
    else      { op[0]+=o0; op[1]+=o1; }
  }
}

extern "C" void kernel_launch(void* const* d_in, const int* in_sizes, int n_in,
                              void* d_out, int out_size, void* d_ws, size_t ws_size,
                              hipStream_t stream)
{
  const float* x     = (const float*)d_in[0];
  const float* Wg    = (const float*)d_in[1];
  const float* bg    = (const float*)d_in[2];
  const float* Wv    = (const float*)d_in[3];
  const float* bv    = (const float*)d_in[4];
  const float* Wd    = (const float*)d_in[5];
  const float* bd    = (const float*)d_in[6];
  const float* Wgate = (const float*)d_in[7];
  float* out = (float*)d_out;

  const size_t DD       = (size_t)D_MODEL*D_MODEL;          // 1M elements
  const size_t wtok_b   = (size_t)NTOK*E_EXP*4;             // 256 KiB
  const size_t xbf_b    = (size_t)NTOK*D_MODEL*2;           // 32 MiB
  const size_t w_per_e  = 3*DD*2;                           // 6 MiB (3 matrices)
  const size_t xs_per_e = (size_t)NTOK*D_MODEL*2;           // 32 MiB
  const size_t st_per_e = (size_t)B_BATCH*NCHUNK*D_MODEL*4; // 2 MiB

  int G = 1;
  for (int g = 4; g >= 1; g >>= 1){
    size_t need = wtok_b + xbf_b + (size_t)g*(w_per_e + 2*xs_per_e + 3*st_per_e);
    if (need <= ws_size){ G = g; break; }
  }

  char* wsb = (char*)d_ws;
  size_t off = 0;
  float*          wtok = (float*)(wsb+off);          off += wtok_b;
  unsigned short* xbf  = (unsigned short*)(wsb+off); off += xbf_b;
  unsigned short* Wcat = (unsigned short*)(wsb+off); off += (size_t)G*w_per_e;
  unsigned short* xs   = (unsigned short*)(wsb+off); off += (size_t)G*xs_per_e;
  unsigned short* aa   = (unsigned short*)(wsb+off); off += (size_t)G*xs_per_e;
  float*          P    = (float*)(wsb+off);          off += (size_t)G*st_per_e;
  float*          U    = (float*)(wsb+off);          off += (size_t)G*st_per_e;
  float*          Hi   = (float*)(wsb+off);

  cvt_bf16<<<(unsigned)((size_t)NTOK*D_MODEL/1024), 256, 0, stream>>>(x, xbf);
  router_kernel<<<NTOK/4, 256, 0, stream>>>(x, Wgate, wtok);

  for (int e0=0; e0<E_EXP; e0+=G){
    unsigned cvg = (unsigned)((size_t)G*DD/1024);
    cvt_w<<<cvg, 256, 0, stream>>>(Wg, Wcat, e0, 0);
    cvt_w<<<cvg, 256, 0, stream>>>(Wv, Wcat, e0, 1);
    cvt_w<<<cvg, 256, 0, stream>>>(Wd, Wcat, e0, 2);

    dim3 gg(NTOK/BM, D_MODEL/BN, G);
    gemm_fused<<<gg, 256, 0, stream>>>(xbf, Wcat, bg, bv, bd, xs, aa, e0);

    scan_pass1<<<G*B_BATCH*NCHUNK, 512, 0, stream>>>(xs, aa, P, U);
    scan_pass2<<<G*B_BATCH*D_MODEL/256, 256, 0, stream>>>(P, U, Hi);
    bool first = (e0 == 0);
    if (G==4)      scan_pass3<4,1><<<B_BATCH*NCHUNK, 512, 0, stream>>>(xs, aa, Hi, wtok, out, e0);
    else if (G==2){
      if (first) scan_pass3<2,1><<<B_BATCH*NCHUNK, 512, 0, stream>>>(xs, aa, Hi, wtok, out, e0);
      else       scan_pass3<2,0><<<B_BATCH*NCHUNK, 512, 0, stream>>>(xs, aa, Hi, wtok, out, e0);
    } else {
      if (first) scan_pass3<1,1><<<B_BATCH*NCHUNK, 512, 0, stream>>>(xs, aa, Hi, wtok, out, e0);
      else       scan_pass3<1,0><<<B_BATCH*NCHUNK, 512, 0, stream>>>(xs, aa, Hi, wtok, out, e0);
    }
  }
}

// Round 4
// 905.230 us; speedup vs baseline: 1.5014x; 1.5014x over previous
//
#include <hip/hip_runtime.h>

#define E_EXP 4
#define D_MODEL 1024
#define B_BATCH 4
#define S_SEQ 4096
#define NTOK (B_BATCH*S_SEQ)   // 16384
#define CHUNK 32
#define NCHUNK (S_SEQ/CHUNK)   // 128

typedef float f4 __attribute__((ext_vector_type(4)));
typedef float f32x4 __attribute__((ext_vector_type(4)));
typedef short bf16x8 __attribute__((ext_vector_type(8)));

__device__ __forceinline__ unsigned short f2b(float f){
  union{float f;unsigned u;}v; v.f=f;
  unsigned r = v.u + 0x7fffu + ((v.u>>16)&1u);
  return (unsigned short)(r>>16);
}
__device__ __forceinline__ float b2f_lo(unsigned v){ union{unsigned u;float f;}x; x.u=v<<16; return x.f; }
__device__ __forceinline__ float b2f_hi(unsigned v){ union{unsigned u;float f;}x; x.u=v&0xffff0000u; return x.f; }

__device__ __forceinline__ void gload_lds16(const void* g, void* l){
  __builtin_amdgcn_global_load_lds(
      (const __attribute__((address_space(1))) void*)g,
      (__attribute__((address_space(3))) void*)l, 16, 0, 0);
}

// ---------------- fp32 -> bf16 conversion (flat) ----------------
__global__ __launch_bounds__(256) void cvt_bf16(const float* __restrict__ src,
                                                unsigned short* __restrict__ dst)
{
  size_t i = ((size_t)blockIdx.x*256 + threadIdx.x)*4;
  f4 v = *(const f4*)(src + i);
  ushort4 o; o.x=f2b(v[0]); o.y=f2b(v[1]); o.z=f2b(v[2]); o.w=f2b(v[3]);
  *(ushort4*)(dst + i) = o;
}

// Wg/Wv/Wd expert slices -> Wcat[le][3][D][D] bf16
__global__ __launch_bounds__(256) void cvt_w3(const float* __restrict__ Wg,
                                              const float* __restrict__ Wv,
                                              const float* __restrict__ Wd,
                                              unsigned short* __restrict__ Wcat,
                                              int e0)
{
  const size_t DD = (size_t)D_MODEL*D_MODEL;   // 2^20
  size_t i4 = ((size_t)blockIdx.x*256 + threadIdx.x)*4;
  size_t le3m = i4 >> 20;          // / DD
  size_t rem  = i4 & (DD-1);
  int mat = (int)(le3m % 3);
  int le  = (int)(le3m / 3);
  const float* src = (mat==0 ? Wg : (mat==1 ? Wv : Wd)) + (size_t)(e0+le)*DD + rem;
  f4 v = *(const f4*)src;
  ushort4 o; o.x=f2b(v[0]); o.y=f2b(v[1]); o.z=f2b(v[2]); o.w=f2b(v[3]);
  *(ushort4*)(Wcat + le3m*DD + rem) = o;
}

// ---------------- router: top-2 softmax gate weights per token ----------------
__global__ __launch_bounds__(256) void router_kernel(
    const float* __restrict__ x, const float* __restrict__ Wgate,
    float* __restrict__ wtok)
{
  int gtid = blockIdx.x*256 + threadIdx.x;
  int tok  = gtid >> 6;
  int lane = threadIdx.x & 63;
  const float* xr = x + (size_t)tok * D_MODEL;
  float acc0=0.f,acc1=0.f,acc2=0.f,acc3=0.f;
  for (int k=lane;k<D_MODEL;k+=64){
    float xv = xr[k];
    acc0 += xv*Wgate[0*D_MODEL+k];
    acc1 += xv*Wgate[1*D_MODEL+k];
    acc2 += xv*Wgate[2*D_MODEL+k];
    acc3 += xv*Wgate[3*D_MODEL+k];
  }
  #pragma unroll
  for (int off=32;off>0;off>>=1){
    acc0 += __shfl_down(acc0,off);
    acc1 += __shfl_down(acc1,off);
    acc2 += __shfl_down(acc2,off);
    acc3 += __shfl_down(acc3,off);
  }
  if (lane==0){
    float l[4]={acc0,acc1,acc2,acc3};
    int i1=0;
    #pragma unroll
    for(int e=1;e<4;e++) if (l[e]>l[i1]) i1=e;
    int i2=-1;
    #pragma unroll
    for(int e=0;e<4;e++){ if(e==i1) continue; if(i2<0||l[e]>l[i2]) i2=e; }
    float ex = __expf(l[i2]-l[i1]);
    float w1 = 1.f/(1.f+ex);
    float w2 = ex/(1.f+ex);
    float w[4]={0.f,0.f,0.f,0.f};
    w[i1]=w1; w[i2]=w2;
    float* wp = wtok + (size_t)tok*E_EXP;
    wp[0]=w[0]; wp[1]=w[1]; wp[2]=w[2]; wp[3]=w[3];
  }
}

// ---------------- pure bf16 MFMA GEMM, N-concat over {g,v,d}, swizzled LDS ----------------
// gvd[(le*3+mat)][m][n] = sum_k x[m,k]*W[mat,n,k]   (raw, no bias/activation)
#define BM 128
#define BN 128
#define BK 32

__global__ __launch_bounds__(256) void gemm_3n(
    const unsigned short* __restrict__ A,     // xbf [NTOK][D]
    const unsigned short* __restrict__ Wcat,  // [G][3][D][D] bf16
    unsigned short* __restrict__ gvd)         // [G][3][NTOK][D] bf16 raw
{
  __shared__ unsigned short sA[BM*BK];   // 8 KB
  __shared__ unsigned short sB[BN*BK];   // 8 KB
  const size_t DD = (size_t)D_MODEL*D_MODEL;
  const size_t ND = (size_t)NTOK*D_MODEL;

  int le    = blockIdx.z;
  int mbase = blockIdx.x*BM;
  int ntile = blockIdx.y;                // 0..23
  int mat   = ntile>>3;                  // which matrix (g/v/d)
  int nbase = (ntile&7)*BN;              // col within matrix
  int tid  = threadIdx.x;
  int wave = tid>>6, lane = tid&63;
  int wm = wave>>1, wn = wave&1;         // wave tile 64x64

  const unsigned short* Wmat = Wcat + ((size_t)le*3 + mat)*DD;

  // ---- staging with XOR swizzle: row r's 16B-chunk slot c holds logical chunk c^((r>>1)&3)
  // each gload_lds16 covers 16 rows x 64B; lane l -> local row R0+(l>>2), slot l&3
  int src_chunk = (lane&3) ^ ((lane>>3)&3);        // logical chunk this lane fetches
  int srow = lane>>2;                              // row within 16-row group
  const unsigned short* gA0 = A    + (size_t)(mbase + wave*32 + srow)*D_MODEL + src_chunk*8;
  const unsigned short* gA1 = gA0  + (size_t)16*D_MODEL;
  const unsigned short* gB0 = Wmat + (size_t)(nbase + wave*32 + srow)*D_MODEL + src_chunk*8;
  const unsigned short* gB1 = gB0  + (size_t)16*D_MODEL;
  unsigned short* lA0 = &sA[(wave*32)*BK];
  unsigned short* lA1 = &sA[(wave*32+16)*BK];
  unsigned short* lB0 = &sB[(wave*32)*BK];
  unsigned short* lB1 = &sB[(wave*32+16)*BK];

  f32x4 acc[4][4];
  #pragma unroll
  for (int i=0;i<4;i++)
    #pragma unroll
    for (int j=0;j<4;j++) acc[i][j] = 0;

  // fragment read addressing (swizzle-aware): swiz depends only on lane bits 1-2
  int swiz   = (lane>>1)&3;
  int rd_chk = ((lane>>4) ^ swiz)*8;               // ushort offset of 16B chunk
  int a_base = (wm*64 + (lane&15))*BK + rd_chk;
  int b_base = (wn*64 + (lane&15))*BK + rd_chk;

  for (int k0=0; k0<D_MODEL; k0+=BK){
    gload_lds16(gA0 + k0, lA0);
    gload_lds16(gA1 + k0, lA1);
    gload_lds16(gB0 + k0, lB0);
    gload_lds16(gB1 + k0, lB1);
    __syncthreads();
    bf16x8 af[4], bfv[4];
    #pragma unroll
    for (int mi=0;mi<4;mi++) af[mi]  = *(const bf16x8*)&sA[a_base + mi*16*BK];
    #pragma unroll
    for (int ni=0;ni<4;ni++) bfv[ni] = *(const bf16x8*)&sB[b_base + ni*16*BK];
    #pragma unroll
    for (int mi=0;mi<4;mi++)
      #pragma unroll
      for (int ni=0;ni<4;ni++)
        acc[mi][ni] = __builtin_amdgcn_mfma_f32_16x16x32_bf16(af[mi], bfv[ni], acc[mi][ni], 0, 0, 0);
    __syncthreads();
  }

  // light epilogue: raw bf16 store (C/D layout col=lane&15, row=(lane>>4)*4+r)
  unsigned short* outp = gvd + ((size_t)le*3 + mat)*ND;
  int me = mbase + wm*64;
  int ne = nbase + wn*64;
  #pragma unroll
  for (int mi=0;mi<4;mi++){
    #pragma unroll
    for (int r=0;r<4;r++){
      int m = me + mi*16 + (lane>>4)*4 + r;
      size_t rowoff = (size_t)m*D_MODEL;
      #pragma unroll
      for (int ni=0;ni<4;ni++){
        int n = ne + ni*16 + (lane&15);
        outp[rowoff+n] = f2b(acc[mi][ni][r]);
      }
    }
  }
}

// ---------------- pass 1: bias+activation + local chunk scan; writes xs,aa in place ----------------
__global__ __launch_bounds__(512) void scan_pass1(
    unsigned short* __restrict__ gvd,   // [G][3][NTOK][D]; g-plane becomes xs, d-plane becomes aa
    const float* __restrict__ bg, const float* __restrict__ bv, const float* __restrict__ bd,
    float* __restrict__ P, float* __restrict__ U, int e0)
{
  const size_t ND = (size_t)NTOK*D_MODEL;
  int blk = blockIdx.x;
  int c  = blk % NCHUNK;
  int b  = (blk / NCHUNK) % B_BATCH;
  int le = blk / (NCHUNK*B_BATCH);
  int d0 = threadIdx.x*2;
  int e  = e0 + le;

  float bg0 = bg[(size_t)e*D_MODEL+d0], bg1 = bg[(size_t)e*D_MODEL+d0+1];
  float bv0 = bv[(size_t)e*D_MODEL+d0], bv1 = bv[(size_t)e*D_MODEL+d0+1];
  float bd0 = bd[(size_t)e*D_MODEL+d0], bd1 = bd[(size_t)e*D_MODEL+d0+1];

  unsigned short* gp = gvd + (size_t)le*3*ND;      // g plane (-> xs)
  size_t base = (((size_t)b)*S_SEQ + (size_t)c*CHUNK)*D_MODEL + d0;
  float h0=0.f,h1=0.f,p0=1.f,p1=1.f;
  for (int t=0;t<CHUNK;t++){
    unsigned gw = *(const unsigned*)(gp + base);
    unsigned vw = *(const unsigned*)(gp + ND + base);
    unsigned dw = *(const unsigned*)(gp + 2*ND + base);
    float g0 = b2f_lo(gw)+bg0, g1 = b2f_hi(gw)+bg1;
    float v0 = b2f_lo(vw)+bv0, v1 = b2f_hi(vw)+bv1;
    float dd0 = b2f_lo(dw)+bd0, dd1 = b2f_hi(dw)+bd1;
    float x0 = (1.f/(1.f+__expf(-g0))) * (1.f - 2.f/(__expf(2.f*v0)+1.f));
    float x1 = (1.f/(1.f+__expf(-g1))) * (1.f - 2.f/(__expf(2.f*v1)+1.f));
    float a0 = 0.001f + 0.998f/(1.f+__expf(-dd0));
    float a1 = 0.001f + 0.998f/(1.f+__expf(-dd1));
    h0 = a0*h0 + x0; h1 = a1*h1 + x1;
    p0 *= a0; p1 *= a1;
    unsigned xsw = (unsigned)f2b(x0) | ((unsigned)f2b(x1)<<16);
    unsigned aaw = (unsigned)f2b(a0) | ((unsigned)f2b(a1)<<16);
    *(unsigned*)(gp + base)        = xsw;   // xs over g-plane
    *(unsigned*)(gp + 2*ND + base) = aaw;   // aa over d-plane
    base += D_MODEL;
  }
  size_t sidx = (((size_t)(le*B_BATCH + b))*NCHUNK + c)*D_MODEL + d0;
  P[sidx]=p0; P[sidx+1]=p1;
  U[sidx]=h0; U[sidx+1]=h1;
}

// ---------------- pass 2: sequential combine over chunks -> Hinit per chunk ----------------
__global__ __launch_bounds__(256) void scan_pass2(
    const float* __restrict__ P, const float* __restrict__ U, float* __restrict__ Hinit)
{
  int ch = blockIdx.x*256 + threadIdx.x;
  int d  = ch & (D_MODEL-1);
  int eb = ch >> 10;
  size_t base = (size_t)eb*NCHUNK*D_MODEL + d;
  float H=0.f;
  for (int c=0;c<NCHUNK;c++){
    size_t idx = base + (size_t)c*D_MODEL;
    Hinit[idx] = H;
    H = P[idx]*H + U[idx];
  }
}

// ---------------- pass 3: re-scan + fused top-2 weighted combine ----------------
template<int G, int FIRST>
__global__ __launch_bounds__(512) void scan_pass3(
    const unsigned short* __restrict__ gvd,   // xs = plane le*3, aa = plane le*3+2
    const float* __restrict__ Hinit, const float* __restrict__ wtok,
    float* __restrict__ out, int e0)
{
  const size_t ND = (size_t)NTOK*D_MODEL;
  int blk = blockIdx.x;
  int c = blk % NCHUNK;
  int b = blk / NCHUNK;
  int d0 = threadIdx.x*2;
  float h[G][2];
  #pragma unroll
  for (int le=0; le<G; le++){
    size_t hi = (((size_t)(le*B_BATCH+b))*NCHUNK + c)*D_MODEL + d0;
    h[le][0]=Hinit[hi]; h[le][1]=Hinit[hi+1];
  }
  int s0 = c*CHUNK;
  for (int t=0;t<CHUNK;t++){
    size_t n = (size_t)b*S_SEQ + s0 + t;
    float o0=0.f, o1=0.f;
    #pragma unroll
    for (int le=0;le<G;le++){
      float w = wtok[n*E_EXP + e0 + le];
      size_t idx = (size_t)le*3*ND + n*D_MODEL + d0;
      unsigned xv = *(const unsigned*)(gvd + idx);
      unsigned av = *(const unsigned*)(gvd + 2*ND + idx);
      h[le][0] = b2f_lo(av)*h[le][0] + b2f_lo(xv);
      h[le][1] = b2f_hi(av)*h[le][1] + b2f_hi(xv);
      o0 += w*h[le][0];
      o1 += w*h[le][1];
    }
    float* op = out + n*D_MODEL + d0;
    if (FIRST){ op[0]=o0;  op[1]=o1;  }
    else      { op[0]+=o0; op[1]+=o1; }
  }
}

extern "C" void kernel_launch(void* const* d_in, const int* in_sizes, int n_in,
                              void* d_out, int out_size, void* d_ws, size_t ws_size,
                              hipStream_t stream)
{
  const float* x     = (const float*)d_in[0];
  const float* Wg    = (const float*)d_in[1];
  const float* bg    = (const float*)d_in[2];
  const float* Wv    = (const float*)d_in[3];
  const float* bv    = (const float*)d_in[4];
  const float* Wd    = (const float*)d_in[5];
  const float* bd    = (const float*)d_in[6];
  const float* Wgate = (const float*)d_in[7];
  float* out = (float*)d_out;

  const size_t DD        = (size_t)D_MODEL*D_MODEL;
  const size_t ND        = (size_t)NTOK*D_MODEL;
  const size_t wtok_b    = (size_t)NTOK*E_EXP*4;             // 256 KiB
  const size_t xbf_b     = ND*2;                             // 32 MiB
  const size_t w_per_e   = 3*DD*2;                           // 6 MiB
  const size_t gvd_per_e = 3*ND*2;                           // 96 MiB
  const size_t st_per_e  = (size_t)B_BATCH*NCHUNK*D_MODEL*4; // 2 MiB

  int G = 1;
  for (int g = 4; g >= 1; g >>= 1){
    size_t need = wtok_b + xbf_b + (size_t)g*(w_per_e + gvd_per_e + 3*st_per_e);
    if (need <= ws_size){ G = g; break; }
  }

  char* wsb = (char*)d_ws;
  size_t off = 0;
  float*          wtok = (float*)(wsb+off);          off += wtok_b;
  unsigned short* xbf  = (unsigned short*)(wsb+off); off += xbf_b;
  unsigned short* Wcat = (unsigned short*)(wsb+off); off += (size_t)G*w_per_e;
  unsigned short* gvd  = (unsigned short*)(wsb+off); off += (size_t)G*gvd_per_e;
  float*          P    = (float*)(wsb+off);          off += (size_t)G*st_per_e;
  float*          U    = (float*)(wsb+off);          off += (size_t)G*st_per_e;
  float*          Hi   = (float*)(wsb+off);

  cvt_bf16<<<(unsigned)(ND/1024), 256, 0, stream>>>(x, xbf);
  router_kernel<<<NTOK/4, 256, 0, stream>>>(x, Wgate, wtok);

  for (int e0=0; e0<E_EXP; e0+=G){
    cvt_w3<<<(unsigned)((size_t)G*3*DD/1024), 256, 0, stream>>>(Wg, Wv, Wd, Wcat, e0);

    dim3 gg(NTOK/BM, 3*D_MODEL/BN, G);
    gemm_3n<<<gg, 256, 0, stream>>>(xbf, Wcat, gvd);

    scan_pass1<<<G*B_BATCH*NCHUNK, 512, 0, stream>>>(gvd, bg, bv, bd, P, U, e0);
    scan_pass2<<<G*B_BATCH*D_MODEL/256, 256, 0, stream>>>(P, U, Hi);
    bool first = (e0 == 0);
    if (G==4)      scan_pass3<4,1><<<B_BATCH*NCHUNK, 512, 0, stream>>>(gvd, Hi, wtok, out, e0);
    else if (G==2){
      if (first) scan_pass3<2,1><<<B_BATCH*NCHUNK, 512, 0, stream>>>(gvd, Hi, wtok, out, e0);
      else       scan_pass3<2,0><<<B_BATCH*NCHUNK, 512, 0, stream>>>(gvd, Hi, wtok, out, e0);
    } else {
      if (first) scan_pass3<1,1><<<B_BATCH*NCHUNK, 512, 0, stream>>>(gvd, Hi, wtok, out, e0);
      else       scan_pass3<1,0><<<B_BATCH*NCHUNK, 512, 0, stream>>>(gvd, Hi, wtok, out, e0);
    }
  }
}